// Round 2
// baseline (333.156 us; speedup 1.0000x reference)
//
#include <hip/hip_runtime.h>
#include <hip/hip_bf16.h>
#include <stdint.h>

// HQQLinear: out = x @ dequant(W_q, scale, zero)^T + bias
// x: [8,512,4096] f32 -> M=4096 rows. W_est: [4096][4096]. out f32 [4096][4096].
//
// Structure: (1) x -> bf16, (2) W_q nibbles -> bf16 W_est (row-major, K contig),
// (3) m97-structure bf16 GEMM: 128x128 tile, BK=32, global_load_lds(16B),
//     16x16x32 MFMA, 4x4 frags/wave, bias fused in epilogue.

#define IN_F  4096
#define OUT_F 4096
#define MROWS 4096

#define BM 128
#define BN 128
#define BK 32

typedef __attribute__((ext_vector_type(8))) __bf16 bf16x8;
typedef __attribute__((ext_vector_type(4))) float f32x4;

__device__ __forceinline__ ushort f2bf(float f) {
    uint32_t u = __float_as_uint(f);
    u += 0x7fffu + ((u >> 16) & 1u);   // round-to-nearest-even
    return (ushort)(u >> 16);
}

// ---------------- kernel 1: x fp32 -> bf16 ----------------
__global__ void conv_x(const float* __restrict__ x, ushort* __restrict__ xb, int n) {
    int i = (blockIdx.x * blockDim.x + threadIdx.x) * 4;
    if (i >= n) return;
    float4 v = *(const float4*)(x + i);
    ushort4 o = make_ushort4(f2bf(v.x), f2bf(v.y), f2bf(v.z), f2bf(v.w));
    *(ushort4*)(xb + i) = o;
}

// ---------------- kernel 2: dequant W_q -> bf16 W_est[4096][4096] ----------------
// W_q flat [32][262144] int32. chunk t handles 4 consecutive ints.
// p = row (0..31), c = col, j = c/4096, i = c%4096.
// hi nibble -> W_est[p*64 + j][i], lo nibble -> W_est[(p+32)*64 + j][i].
__global__ void dequant(const int* __restrict__ Wq, const float* __restrict__ scale,
                        const float* __restrict__ zero, ushort* __restrict__ West) {
    int t = blockIdx.x * blockDim.x + threadIdx.x;   // 2,097,152 threads
    int flat = t << 2;
    int p = flat >> 18;          // /262144
    int c = flat & 262143;
    int j = c >> 12;             // /4096
    int i = c & 4095;

    int4 q = *(const int4*)(Wq + flat);
    float4 sc = *(const float4*)(scale + c);
    float4 zr = *(const float4*)(zero + c);

    int   qv[4] = {q.x, q.y, q.z, q.w};
    float sv[4] = {sc.x, sc.y, sc.z, sc.w};
    float zv[4] = {zr.x, zr.y, zr.z, zr.w};

    ushort hi[4], lo[4];
#pragma unroll
    for (int e = 0; e < 4; ++e) {
        float h = ((float)((qv[e] >> 4) & 0xF) - zv[e]) * sv[e];
        float l = ((float)(qv[e] & 0xF) - zv[e]) * sv[e];
        hi[e] = f2bf(h);
        lo[e] = f2bf(l);
    }
    size_t o_hi = (size_t)(p * 64 + j) * IN_F + i;
    size_t o_lo = (size_t)((p + 32) * 64 + j) * IN_F + i;
    *(ushort4*)(West + o_hi) = make_ushort4(hi[0], hi[1], hi[2], hi[3]);
    *(ushort4*)(West + o_lo) = make_ushort4(lo[0], lo[1], lo[2], lo[3]);
}

// ---------------- kernel 3: bf16 GEMM, C = A * B^T + bias ----------------
// A [M][K] bf16, B [N][K] bf16 (both row-major, K contiguous), C [M][N] f32.
__device__ __forceinline__ void gload16(const ushort* g, const ushort* l) {
    __builtin_amdgcn_global_load_lds((const __attribute__((address_space(1))) void*)g,
                                     (__attribute__((address_space(3))) void*)l,
                                     16, 0, 0);
}

__global__ __launch_bounds__(256) void gemm_bt(const ushort* __restrict__ A,
                                               const ushort* __restrict__ B,
                                               const float* __restrict__ bias,
                                               float* __restrict__ C) {
    __shared__ alignas(16) ushort As[BM][BK];
    __shared__ alignas(16) ushort Bs[BN][BK];

    const int tid  = threadIdx.x;
    const int wave = tid >> 6;
    const int lane = tid & 63;
    const int m0 = blockIdx.y * BM;
    const int n0 = blockIdx.x * BN;
    const int wr = wave >> 1;   // wave row (0..1): 64 rows of C each
    const int wc = wave & 1;    // wave col (0..1): 64 cols of C each

    f32x4 zero4 = {0.f, 0.f, 0.f, 0.f};
    f32x4 acc[4][4];
#pragma unroll
    for (int mi = 0; mi < 4; ++mi)
#pragma unroll
        for (int ni = 0; ni < 4; ++ni) acc[mi][ni] = zero4;

    for (int k0 = 0; k0 < IN_F; k0 += BK) {
        // ---- stage A,B tiles via global_load_lds (16B/lane) ----
        // 512 chunks of 16B per tile; wave w covers chunks [w*128, w*128+128)
#pragma unroll
        for (int q = 0; q < 2; ++q) {
            int p  = wave * 128 + q * 64 + lane;
            int r  = p >> 2;
            int kk = (p & 3) << 3;
            gload16(A + (size_t)(m0 + r) * IN_F + k0 + kk,
                    &As[0][0] + (size_t)wave * 1024 + q * 512);  // ushort units: 2048B/wave
        }
#pragma unroll
        for (int q = 0; q < 2; ++q) {
            int p  = wave * 128 + q * 64 + lane;
            int r  = p >> 2;
            int kk = (p & 3) << 3;
            gload16(B + (size_t)(n0 + r) * IN_F + k0 + kk,
                    &Bs[0][0] + (size_t)wave * 1024 + q * 512);
        }
        __syncthreads();   // compiler emits s_waitcnt vmcnt(0) before s_barrier

        // ---- fragments + MFMA ----
        bf16x8 a[4], b[4];
#pragma unroll
        for (int mi = 0; mi < 4; ++mi)
            a[mi] = *(const bf16x8*)(&As[wr * 64 + mi * 16 + (lane & 15)][(lane >> 4) * 8]);
#pragma unroll
        for (int ni = 0; ni < 4; ++ni)
            b[ni] = *(const bf16x8*)(&Bs[wc * 64 + ni * 16 + (lane & 15)][(lane >> 4) * 8]);
#pragma unroll
        for (int mi = 0; mi < 4; ++mi)
#pragma unroll
            for (int ni = 0; ni < 4; ++ni)
                acc[mi][ni] = __builtin_amdgcn_mfma_f32_16x16x32_bf16(a[mi], b[ni], acc[mi][ni], 0, 0, 0);
        __syncthreads();   // protect LDS before next stage overwrites
    }

    // ---- epilogue: C = acc + bias, C/D layout col=lane&15, row=(lane>>4)*4+v ----
#pragma unroll
    for (int ni = 0; ni < 4; ++ni) {
        int n = n0 + wc * 64 + ni * 16 + (lane & 15);
        float bv = bias[n];
#pragma unroll
        for (int mi = 0; mi < 4; ++mi) {
            int mbase = m0 + wr * 64 + mi * 16 + ((lane >> 4) << 2);
#pragma unroll
            for (int v = 0; v < 4; ++v) {
                C[(size_t)(mbase + v) * OUT_F + n] = acc[mi][ni][v] + bv;
            }
        }
    }
}

extern "C" void kernel_launch(void* const* d_in, const int* in_sizes, int n_in,
                              void* d_out, int out_size, void* d_ws, size_t ws_size,
                              hipStream_t stream) {
    const float* x     = (const float*)d_in[0];
    const int*   Wq    = (const int*)d_in[1];
    const float* scale = (const float*)d_in[2];
    const float* zero  = (const float*)d_in[3];
    const float* bias  = (const float*)d_in[4];
    float* out = (float*)d_out;

    ushort* xb   = (ushort*)d_ws;                            // 32 MB: x as bf16
    ushort* West = (ushort*)d_ws + (size_t)MROWS * IN_F;     // 32 MB: W_est bf16

    conv_x<<<(MROWS * IN_F / 4 + 255) / 256, 256, 0, stream>>>(x, xb, MROWS * IN_F);
    dequant<<<(32 * 262144 / 4 + 255) / 256, 256, 0, stream>>>(Wq, scale, zero, West);

    dim3 grid(OUT_F / BN, MROWS / BM);
    gemm_bt<<<grid, 256, 0, stream>>>(xb, West, bias, out);
}

// Round 3
// 277.737 us; speedup vs baseline: 1.1995x; 1.1995x over previous
//
#include <hip/hip_runtime.h>
#include <hip/hip_bf16.h>
#include <stdint.h>

// HQQLinear: out = x @ dequant(W_q)^T + bias.
// (1) x f32->bf16  (2) W_q nibbles -> bf16 W_est[4096][4096]
// (3) 256x256x64 8-phase bf16 GEMM (m201 template): 8 waves, 128KiB LDS dbuf,
//     K-split LDS layout (conflict-free ds_read_b128 + linear gload_lds),
//     counted vmcnt(4), raw s_barrier, setprio around MFMA clusters.

#define IN_F  4096
#define OUT_F 4096
#define MROWS 4096

#define BM 256
#define BN 256
#define BK 64
#define NT (IN_F / BK)   // 64 K-tiles

typedef __attribute__((ext_vector_type(8))) __bf16 bf16x8;
typedef __attribute__((ext_vector_type(4))) float f32x4;

__device__ __forceinline__ ushort f2bf(float f) {
    uint32_t u = __float_as_uint(f);
    u += 0x7fffu + ((u >> 16) & 1u);   // RNE
    return (ushort)(u >> 16);
}

// ---------------- kernel 1: x fp32 -> bf16 ----------------
__global__ void conv_x(const float* __restrict__ x, ushort* __restrict__ xb, int n) {
    int i = (blockIdx.x * blockDim.x + threadIdx.x) * 4;
    if (i >= n) return;
    float4 v = *(const float4*)(x + i);
    *(ushort4*)(xb + i) = make_ushort4(f2bf(v.x), f2bf(v.y), f2bf(v.z), f2bf(v.w));
}

// ---------------- kernel 2: dequant W_q -> bf16 W_est ----------------
__global__ void dequant(const int* __restrict__ Wq, const float* __restrict__ scale,
                        const float* __restrict__ zero, ushort* __restrict__ West) {
    int t = blockIdx.x * blockDim.x + threadIdx.x;
    int flat = t << 2;
    int p = flat >> 18;
    int c = flat & 262143;
    int j = c >> 12;
    int i = c & 4095;

    int4 q = *(const int4*)(Wq + flat);
    float4 sc = *(const float4*)(scale + c);
    float4 zr = *(const float4*)(zero + c);

    int   qv[4] = {q.x, q.y, q.z, q.w};
    float sv[4] = {sc.x, sc.y, sc.z, sc.w};
    float zv[4] = {zr.x, zr.y, zr.z, zr.w};

    ushort hi[4], lo[4];
#pragma unroll
    for (int e = 0; e < 4; ++e) {
        hi[e] = f2bf(((float)((qv[e] >> 4) & 0xF) - zv[e]) * sv[e]);
        lo[e] = f2bf(((float)(qv[e] & 0xF) - zv[e]) * sv[e]);
    }
    size_t o_hi = (size_t)(p * 64 + j) * IN_F + i;
    size_t o_lo = (size_t)((p + 32) * 64 + j) * IN_F + i;
    *(ushort4*)(West + o_hi) = make_ushort4(hi[0], hi[1], hi[2], hi[3]);
    *(ushort4*)(West + o_lo) = make_ushort4(lo[0], lo[1], lo[2], lo[3]);
}

// ---------------- kernel 3: 256^2 8-phase bf16 GEMM ----------------
__device__ __forceinline__ void gload16(const ushort* g, const ushort* l) {
    __builtin_amdgcn_global_load_lds((const __attribute__((address_space(1))) void*)g,
                                     (__attribute__((address_space(3))) void*)l,
                                     16, 0, 0);
}

// LDS (ushort units): buf b at b*32768. Within buf: A at 0, B at +16384.
// Within A/B: [khalf][256 rows][32 cols], khalf stride 8192, row stride 32.
// Row stride = 64B -> fragment ds_read_b128 covers all 32 banks uniformly.

#define VMCNT4 asm volatile("s_waitcnt vmcnt(4)" ::: "memory");
#define VMCNT0 asm volatile("s_waitcnt vmcnt(0)" ::: "memory");
#define BAR    __builtin_amdgcn_s_barrier();

#define DS_A(kk, mh)                                                               \
    _Pragma("unroll") for (int mf = 0; mf < 4; ++mf)                               \
        afr[mf] = *(const bf16x8*)&lds[(size_t)b * 32768 + (kk) * 8192 +           \
            (wr * 128 + (mh) * 64 + mf * 16 + (lane & 15)) * 32 + (lane >> 4) * 8];

#define DS_B(kk)                                                                   \
    _Pragma("unroll") for (int nf = 0; nf < 4; ++nf)                               \
        bfr[nf] = *(const bf16x8*)&lds[(size_t)b * 32768 + 16384 + (kk) * 8192 +   \
            (wc * 64 + nf * 16 + (lane & 15)) * 32 + (lane >> 4) * 8];

#define MFMA16(mh)                                                                 \
    __builtin_amdgcn_s_setprio(1);                                                 \
    _Pragma("unroll") for (int mf = 0; mf < 4; ++mf)                               \
    _Pragma("unroll") for (int nf = 0; nf < 4; ++nf)                               \
        acc[(mh) * 4 + mf][nf] = __builtin_amdgcn_mfma_f32_16x16x32_bf16(          \
            afr[mf], bfr[nf], acc[(mh) * 4 + mf][nf], 0, 0, 0);                    \
    __builtin_amdgcn_s_setprio(0);

__global__ __launch_bounds__(512, 2) void gemm_bt(const ushort* __restrict__ A,
                                                  const ushort* __restrict__ B,
                                                  const float* __restrict__ bias,
                                                  float* __restrict__ C) {
    __shared__ alignas(16) ushort lds[65536];   // 128 KiB

    const int tid  = threadIdx.x;
    const int wave = tid >> 6;
    const int lane = tid & 63;

    // XCD-aware swizzle (256 blocks % 8 == 0 -> simple form is bijective)
    int bid = blockIdx.x;
    int swz = (bid & 7) * 32 + (bid >> 3);
    const int m0 = (swz >> 4) * BM;
    const int n0 = (swz & 15) * BN;
    const int wr = wave >> 2;   // 0..1 -> 128 rows each
    const int wc = wave & 3;    // 0..3 -> 64 cols each

    f32x4 acc[8][4];
    f32x4 z4 = {0.f, 0.f, 0.f, 0.f};
#pragma unroll
    for (int i = 0; i < 8; ++i)
#pragma unroll
        for (int j = 0; j < 4; ++j) acc[i][j] = z4;

    // stage one k-half (16KB = 2 gloads/thread). kcol = global k col of the half.
    auto stageA = [&](int nb, int kh, int kcol) {
#pragma unroll
        for (int q = 0; q < 2; ++q) {
            int cu = q * 512 + wave * 64;
            int c  = cu + lane;
            gload16(A + (size_t)(m0 + (c >> 2)) * IN_F + kcol + (c & 3) * 8,
                    &lds[(size_t)nb * 32768 + kh * 8192 + cu * 8]);
        }
    };
    auto stageB = [&](int nb, int kh, int kcol) {
#pragma unroll
        for (int q = 0; q < 2; ++q) {
            int cu = q * 512 + wave * 64;
            int c  = cu + lane;
            gload16(B + (size_t)(n0 + (c >> 2)) * IN_F + kcol + (c & 3) * 8,
                    &lds[(size_t)nb * 32768 + 16384 + kh * 8192 + cu * 8]);
        }
    };

    // prologue: tile 0 -> buf 0 (order matters for the vmcnt ledger)
    stageA(0, 0, 0);
    stageB(0, 0, 0);
    stageA(0, 1, 32);
    stageB(0, 1, 32);
    VMCNT4;   // Ak0,Bk0 landed; Ak1,Bk1 (4) still in flight
    BAR;

    for (int T = 0; T < NT; ++T) {
        const int b  = T & 1;
        const int nb = b ^ 1;
        const int kn = ((T + 1) & (NT - 1)) * BK;   // wraps on last tile (discarded)
        bf16x8 afr[4], bfr[4];

        // ph0: kk=0 mh=0
        DS_B(0) DS_A(0, 0)
        stageA(nb, 0, kn);
        BAR; MFMA16(0) BAR;

        // ph1: kk=0 mh=1
        DS_A(0, 1)
        stageB(nb, 0, kn);
        VMCNT4;   // drains this tile's Ak1,Bk1 (read in ph2/ph3)
        BAR; MFMA16(1) BAR;

        // ph2: kk=1 mh=0
        DS_B(1) DS_A(1, 0)
        stageA(nb, 1, kn + 32);
        BAR; MFMA16(0) BAR;

        // ph3: kk=1 mh=1
        DS_A(1, 1)
        stageB(nb, 1, kn + 32);
        VMCNT4;   // drains next tile's Ak0,Bk0 (read in next ph0/ph1)
        BAR; MFMA16(1) BAR;
    }
    VMCNT0;   // don't end the wave with LDS-DMA in flight

    // epilogue: C = acc + bias. C/D map: col=lane&15, row=(lane>>4)*4+v
#pragma unroll
    for (int nf = 0; nf < 4; ++nf) {
        int col = n0 + wc * 64 + nf * 16 + (lane & 15);
        float bv = bias[col];
#pragma unroll
        for (int mfa = 0; mfa < 8; ++mfa) {
            int rbase = m0 + wr * 128 + mfa * 16 + ((lane >> 4) << 2);
#pragma unroll
            for (int v = 0; v < 4; ++v)
                C[(size_t)(rbase + v) * OUT_F + col] = acc[mfa][nf][v] + bv;
        }
    }
}

extern "C" void kernel_launch(void* const* d_in, const int* in_sizes, int n_in,
                              void* d_out, int out_size, void* d_ws, size_t ws_size,
                              hipStream_t stream) {
    const float* x     = (const float*)d_in[0];
    const int*   Wq    = (const int*)d_in[1];
    const float* scale = (const float*)d_in[2];
    const float* zero  = (const float*)d_in[3];
    const float* bias  = (const float*)d_in[4];
    float* out = (float*)d_out;

    ushort* xb   = (ushort*)d_ws;                            // 32 MB
    ushort* West = (ushort*)d_ws + (size_t)MROWS * IN_F;     // 32 MB

    conv_x<<<(MROWS * IN_F / 4 + 255) / 256, 256, 0, stream>>>(x, xb, MROWS * IN_F);
    dequant<<<(32 * 262144 / 4 + 255) / 256, 256, 0, stream>>>(Wq, scale, zero, West);

    gemm_bt<<<(MROWS / BM) * (OUT_F / BN), 512, 0, stream>>>(xb, West, bias, out);
}

// Round 4
// 272.111 us; speedup vs baseline: 1.2243x; 1.0207x over previous
//
#include <hip/hip_runtime.h>
#include <hip/hip_bf16.h>
#include <stdint.h>

// HQQLinear: out = x @ dequant(W_q)^T + bias.
// (1) x f32->bf16  (2) W_q nibbles -> bf16 W_est[4096][4096]
// (3) 256x256x64 8-phase bf16 GEMM, 8 waves, 128KiB LDS dbuf, counted vmcnt(4),
//     raw s_barrier, setprio, and a DERIVED conflict-free LDS chunk swizzle:
//       slot(r,h) = r*4 + (h ^ ((r>>1)&3))   (16B chunks, h = k-chunk 0..3)
//     Read bank-group = 4(r&1) + (h^((r>>1)&3)) -> all 8 groups exactly twice
//     per 16-lane span => conflict-free ds_read_b128. Staging keeps LINEAR
//     LDS dest (global_load_lds rule) and applies the same involution to the
//     per-lane GLOBAL source address (rule #21: both-sides-or-neither).

#define IN_F  4096
#define OUT_F 4096
#define MROWS 4096

#define BM 256
#define BN 256
#define BK 64
#define NT (IN_F / BK)   // 64 K-tiles

typedef __attribute__((ext_vector_type(8))) __bf16 bf16x8;
typedef __attribute__((ext_vector_type(4))) float f32x4;

__device__ __forceinline__ ushort f2bf(float f) {
    uint32_t u = __float_as_uint(f);
    u += 0x7fffu + ((u >> 16) & 1u);   // RNE
    return (ushort)(u >> 16);
}

// ---------------- kernel 1: x fp32 -> bf16 ----------------
__global__ void conv_x(const float* __restrict__ x, ushort* __restrict__ xb, int n) {
    int i = (blockIdx.x * blockDim.x + threadIdx.x) * 4;
    if (i >= n) return;
    float4 v = *(const float4*)(x + i);
    *(ushort4*)(xb + i) = make_ushort4(f2bf(v.x), f2bf(v.y), f2bf(v.z), f2bf(v.w));
}

// ---------------- kernel 2: dequant W_q -> bf16 W_est ----------------
__global__ void dequant(const int* __restrict__ Wq, const float* __restrict__ scale,
                        const float* __restrict__ zero, ushort* __restrict__ West) {
    int t = blockIdx.x * blockDim.x + threadIdx.x;
    int flat = t << 2;
    int p = flat >> 18;
    int c = flat & 262143;
    int j = c >> 12;
    int i = c & 4095;

    int4 q = *(const int4*)(Wq + flat);
    float4 sc = *(const float4*)(scale + c);
    float4 zr = *(const float4*)(zero + c);

    int   qv[4] = {q.x, q.y, q.z, q.w};
    float sv[4] = {sc.x, sc.y, sc.z, sc.w};
    float zv[4] = {zr.x, zr.y, zr.z, zr.w};

    ushort hi[4], lo[4];
#pragma unroll
    for (int e = 0; e < 4; ++e) {
        hi[e] = f2bf(((float)((qv[e] >> 4) & 0xF) - zv[e]) * sv[e]);
        lo[e] = f2bf(((float)(qv[e] & 0xF) - zv[e]) * sv[e]);
    }
    size_t o_hi = (size_t)(p * 64 + j) * IN_F + i;
    size_t o_lo = (size_t)((p + 32) * 64 + j) * IN_F + i;
    *(ushort4*)(West + o_hi) = make_ushort4(hi[0], hi[1], hi[2], hi[3]);
    *(ushort4*)(West + o_lo) = make_ushort4(lo[0], lo[1], lo[2], lo[3]);
}

// ---------------- kernel 3: 256^2 8-phase bf16 GEMM ----------------
__device__ __forceinline__ void gload16(const ushort* g, const ushort* l) {
    __builtin_amdgcn_global_load_lds((const __attribute__((address_space(1))) void*)g,
                                     (__attribute__((address_space(3))) void*)l,
                                     16, 0, 0);
}

// LDS (ushort units): buf b at b*32768. A at +0, B at +16384.
// Within A/B: [khalf][1024 slots of 16B], khalf stride 8192 ushorts.
// slot(r,h) = r*4 + (h ^ ((r>>1)&3)), r = tile row 0..255, h = k-chunk 0..3.

#define VMCNT4 asm volatile("s_waitcnt vmcnt(4)" ::: "memory");
#define VMCNT0 asm volatile("s_waitcnt vmcnt(0)" ::: "memory");
#define BAR    __builtin_amdgcn_s_barrier();

// fragment reads: r = RBASE + rl, slot*8 ushort offset
#define DS_A(kk, mh)                                                               \
    _Pragma("unroll") for (int mf = 0; mf < 4; ++mf)                               \
        afr[mf] = *(const bf16x8*)&lds[(size_t)b * 32768 + (kk) * 8192 +           \
            ((wr * 128 + (mh) * 64 + mf * 16 + rl) * 4 + hx) * 8];

#define DS_B(kk)                                                                   \
    _Pragma("unroll") for (int nf = 0; nf < 4; ++nf)                               \
        bfr[nf] = *(const bf16x8*)&lds[(size_t)b * 32768 + 16384 + (kk) * 8192 +   \
            ((wc * 64 + nf * 16 + rl) * 4 + hx) * 8];

#define MFMA16(mh)                                                                 \
    __builtin_amdgcn_s_setprio(1);                                                 \
    _Pragma("unroll") for (int mf = 0; mf < 4; ++mf)                               \
    _Pragma("unroll") for (int nf = 0; nf < 4; ++nf)                               \
        acc[(mh) * 4 + mf][nf] = __builtin_amdgcn_mfma_f32_16x16x32_bf16(          \
            afr[mf], bfr[nf], acc[(mh) * 4 + mf][nf], 0, 0, 0);                    \
    __builtin_amdgcn_s_setprio(0);

__global__ __launch_bounds__(512, 2) void gemm_bt(const ushort* __restrict__ A,
                                                  const ushort* __restrict__ B,
                                                  const float* __restrict__ bias,
                                                  float* __restrict__ C) {
    __shared__ alignas(16) ushort lds[65536];   // 128 KiB

    const int tid  = threadIdx.x;
    const int wave = tid >> 6;
    const int lane = tid & 63;
    const int rl   = lane & 15;                  // fragment row-in-16
    const int hh   = lane >> 4;                  // k-chunk
    const int hx   = hh ^ ((rl >> 1) & 3);       // swizzled chunk (read side)

    // XCD-aware swizzle (256 blocks, %8==0 -> bijective)
    int bid = blockIdx.x;
    int swz = (bid & 7) * 32 + (bid >> 3);
    const int m0 = (swz >> 4) * BM;
    const int n0 = (swz & 15) * BN;
    const int wr = wave >> 2;   // 0..1 -> 128 rows each
    const int wc = wave & 3;    // 0..3 -> 64 cols each

    f32x4 acc[8][4];
    f32x4 z4 = {0.f, 0.f, 0.f, 0.f};
#pragma unroll
    for (int i = 0; i < 8; ++i)
#pragma unroll
        for (int j = 0; j < 4; ++j) acc[i][j] = z4;

    // stage one k-half (16KB = 2 gloads/thread). LDS dest LINEAR (slot = cu+lane);
    // global source carries the inverse swizzle: h = (s&3) ^ ((r>>1)&3).
    auto stageA = [&](int nb, int kh, int kcol) {
#pragma unroll
        for (int q = 0; q < 2; ++q) {
            int cu = q * 512 + wave * 64;
            int s  = cu + lane;
            int r  = s >> 2;
            int h  = (s & 3) ^ ((r >> 1) & 3);
            gload16(A + (size_t)(m0 + r) * IN_F + kcol + h * 8,
                    &lds[(size_t)nb * 32768 + kh * 8192 + cu * 8]);
        }
    };
    auto stageB = [&](int nb, int kh, int kcol) {
#pragma unroll
        for (int q = 0; q < 2; ++q) {
            int cu = q * 512 + wave * 64;
            int s  = cu + lane;
            int r  = s >> 2;
            int h  = (s & 3) ^ ((r >> 1) & 3);
            gload16(B + (size_t)(n0 + r) * IN_F + kcol + h * 8,
                    &lds[(size_t)nb * 32768 + 16384 + kh * 8192 + cu * 8]);
        }
    };

    // prologue: tile 0 -> buf 0
    stageA(0, 0, 0);
    stageB(0, 0, 0);
    stageA(0, 1, 32);
    stageB(0, 1, 32);
    VMCNT4;   // Ak0,Bk0 landed; Ak1,Bk1 (4 loads) still in flight
    BAR;

    for (int T = 0; T < NT; ++T) {
        const int b  = T & 1;
        const int nb = b ^ 1;
        const int kn = ((T + 1) & (NT - 1)) * BK;   // wraps on last tile (discarded)
        bf16x8 afr[4], bfr[4];

        // ph0: kk=0 mh=0
        DS_B(0) DS_A(0, 0)
        stageA(nb, 0, kn);
        BAR; MFMA16(0) BAR;

        // ph1: kk=0 mh=1
        DS_A(0, 1)
        stageB(nb, 0, kn);
        VMCNT4;   // drains this tile's Ak1,Bk1 (read in ph2/ph3)
        BAR; MFMA16(1) BAR;

        // ph2: kk=1 mh=0
        DS_B(1) DS_A(1, 0)
        stageA(nb, 1, kn + 32);
        BAR; MFMA16(0) BAR;

        // ph3: kk=1 mh=1
        DS_A(1, 1)
        stageB(nb, 1, kn + 32);
        VMCNT4;   // drains next tile's Ak0,Bk0 (read in next ph0/ph1)
        BAR; MFMA16(1) BAR;
    }
    VMCNT0;   // don't end the wave with LDS-DMA in flight

    // epilogue: C = acc + bias. C/D map: col=lane&15, row=(lane>>4)*4+v
#pragma unroll
    for (int nf = 0; nf < 4; ++nf) {
        int col = n0 + wc * 64 + nf * 16 + rl;
        float bv = bias[col];
#pragma unroll
        for (int mfa = 0; mfa < 8; ++mfa) {
            int rbase = m0 + wr * 128 + mfa * 16 + (hh << 2);
#pragma unroll
            for (int v = 0; v < 4; ++v)
                C[(size_t)(rbase + v) * OUT_F + col] = acc[mfa][nf][v] + bv;
        }
    }
}

extern "C" void kernel_launch(void* const* d_in, const int* in_sizes, int n_in,
                              void* d_out, int out_size, void* d_ws, size_t ws_size,
                              hipStream_t stream) {
    const float* x     = (const float*)d_in[0];
    const int*   Wq    = (const int*)d_in[1];
    const float* scale = (const float*)d_in[2];
    const float* zero  = (const float*)d_in[3];
    const float* bias  = (const float*)d_in[4];
    float* out = (float*)d_out;

    ushort* xb   = (ushort*)d_ws;                            // 32 MB
    ushort* West = (ushort*)d_ws + (size_t)MROWS * IN_F;     // 32 MB

    conv_x<<<(MROWS * IN_F / 4 + 255) / 256, 256, 0, stream>>>(x, xb, MROWS * IN_F);
    dequant<<<(32 * 262144 / 4 + 255) / 256, 256, 0, stream>>>(Wq, scale, zero, West);

    gemm_bt<<<(MROWS / BM) * (OUT_F / BN), 512, 0, stream>>>(xb, West, bias, out);
}

// Round 6
// 268.435 us; speedup vs baseline: 1.2411x; 1.0137x over previous
//
#include <hip/hip_runtime.h>
#include <hip/hip_bf16.h>
#include <stdint.h>

// HQQLinear: out = x @ dequant(W_q)^T + bias.
// (1) prep: x f32->bf16  +  W_q nibbles -> bf16 W_est   (single kernel)
// (2) 256x256x64 8-phase bf16 GEMM, 8 waves, 128KiB LDS dbuf,
//     3-half-tile-deep prefetch with counted vmcnt(6) (m201 ledger),
//     conflict-free LDS chunk swizzle slot(r,h)=r*4+(h^((r>>1)&3)),
//     raw s_barrier, setprio around MFMA clusters, XCD-aware block swizzle.

#define IN_F  4096
#define OUT_F 4096
#define MROWS 4096

#define BM 256
#define BN 256
#define BK 64
#define NT (IN_F / BK)   // 64 K-tiles

typedef __attribute__((ext_vector_type(8))) __bf16 bf16x8;
typedef __attribute__((ext_vector_type(4))) float f32x4;

__device__ __forceinline__ ushort f2bf(float f) {
    uint32_t u = __float_as_uint(f);
    u += 0x7fffu + ((u >> 16) & 1u);   // RNE
    return (ushort)(u >> 16);
}

// ---------------- kernel 1: fused conv_x + dequant ----------------
// blocks [0, CONV_BLK): x f32 -> bf16 (float4 -> ushort4)
// blocks [CONV_BLK, CONV_BLK+DQ_BLK): W_q -> W_est bf16
#define CONV_BLK (MROWS * IN_F / 4 / 256)        // 16384
#define DQ_BLK   (32 * 262144 / 4 / 256)         // 8192

__global__ void prep(const float* __restrict__ x, ushort* __restrict__ xb,
                     const int* __restrict__ Wq, const float* __restrict__ scale,
                     const float* __restrict__ zero, ushort* __restrict__ West) {
    int blk = blockIdx.x;
    if (blk < CONV_BLK) {
        int i = (blk * 256 + threadIdx.x) * 4;
        float4 v = *(const float4*)(x + i);
        *(ushort4*)(xb + i) = make_ushort4(f2bf(v.x), f2bf(v.y), f2bf(v.z), f2bf(v.w));
    } else {
        int t = (blk - CONV_BLK) * 256 + threadIdx.x;
        int flat = t << 2;
        int p = flat >> 18;
        int c = flat & 262143;
        int j = c >> 12;
        int i = c & 4095;

        int4 q = *(const int4*)(Wq + flat);
        float4 sc = *(const float4*)(scale + c);
        float4 zr = *(const float4*)(zero + c);

        int   qv[4] = {q.x, q.y, q.z, q.w};
        float sv[4] = {sc.x, sc.y, sc.z, sc.w};
        float zv[4] = {zr.x, zr.y, zr.z, zr.w};

        ushort hi[4], lo[4];
#pragma unroll
        for (int e = 0; e < 4; ++e) {
            hi[e] = f2bf(((float)((qv[e] >> 4) & 0xF) - zv[e]) * sv[e]);
            lo[e] = f2bf(((float)(qv[e] & 0xF) - zv[e]) * sv[e]);
        }
        size_t o_hi = (size_t)(p * 64 + j) * IN_F + i;
        size_t o_lo = (size_t)((p + 32) * 64 + j) * IN_F + i;
        *(ushort4*)(West + o_hi) = make_ushort4(hi[0], hi[1], hi[2], hi[3]);
        *(ushort4*)(West + o_lo) = make_ushort4(lo[0], lo[1], lo[2], lo[3]);
    }
}

// ---------------- kernel 2: 256^2 8-phase bf16 GEMM ----------------
__device__ __forceinline__ void gload16(const ushort* g, const ushort* l) {
    __builtin_amdgcn_global_load_lds((const __attribute__((address_space(1))) void*)g,
                                     (__attribute__((address_space(3))) void*)l,
                                     16, 0, 0);
}

// LDS (ushort units): buf b at b*32768. A at +0, B at +16384.
// Within A/B: [khalf][1024 slots of 16B], khalf stride 8192 ushorts.
// slot(r,h) = r*4 + (h ^ ((r>>1)&3)), r = tile row 0..255, h = k-chunk 0..3.

#define VMCNT6 asm volatile("s_waitcnt vmcnt(6)" ::: "memory");
#define VMCNT0 asm volatile("s_waitcnt vmcnt(0)" ::: "memory");
#define BAR    __builtin_amdgcn_s_barrier();

#define DS_A(kk, mh)                                                               \
    _Pragma("unroll") for (int mf = 0; mf < 4; ++mf)                               \
        afr[mf] = *(const bf16x8*)&lds[(size_t)b * 32768 + (kk) * 8192 +           \
            ((wr * 128 + (mh) * 64 + mf * 16 + rl) * 4 + hx) * 8];

#define DS_B(kk)                                                                   \
    _Pragma("unroll") for (int nf = 0; nf < 4; ++nf)                               \
        bfr[nf] = *(const bf16x8*)&lds[(size_t)b * 32768 + 16384 + (kk) * 8192 +   \
            ((wc * 64 + nf * 16 + rl) * 4 + hx) * 8];

#define MFMA16(mh)                                                                 \
    __builtin_amdgcn_s_setprio(1);                                                 \
    _Pragma("unroll") for (int mf = 0; mf < 4; ++mf)                               \
    _Pragma("unroll") for (int nf = 0; nf < 4; ++nf)                               \
        acc[(mh) * 4 + mf][nf] = __builtin_amdgcn_mfma_f32_16x16x32_bf16(          \
            afr[mf], bfr[nf], acc[(mh) * 4 + mf][nf], 0, 0, 0);                    \
    __builtin_amdgcn_s_setprio(0);

__global__ __launch_bounds__(512, 2) void gemm_bt(const ushort* __restrict__ A,
                                                  const ushort* __restrict__ B,
                                                  const float* __restrict__ bias,
                                                  float* __restrict__ C) {
    __shared__ alignas(16) ushort lds[65536];   // 128 KiB

    const int tid  = threadIdx.x;
    const int wave = tid >> 6;
    const int lane = tid & 63;
    const int rl   = lane & 15;                  // fragment row-in-16
    const int hh   = lane >> 4;                  // k-chunk
    const int hx   = hh ^ ((rl >> 1) & 3);       // swizzled chunk (read side)

    // XCD-aware swizzle (256 blocks, %8==0 -> bijective)
    int bid = blockIdx.x;
    int swz = (bid & 7) * 32 + (bid >> 3);
    const int m0 = (swz >> 4) * BM;
    const int n0 = (swz & 15) * BN;
    const int wr = wave >> 2;   // 0..1 -> 128 rows each
    const int wc = wave & 3;    // 0..3 -> 64 cols each

    f32x4 acc[8][4];
    f32x4 z4 = {0.f, 0.f, 0.f, 0.f};
#pragma unroll
    for (int i = 0; i < 8; ++i)
#pragma unroll
        for (int j = 0; j < 4; ++j) acc[i][j] = z4;

    // stage one k-half (16KB = 2 gloads/thread). LDS dest LINEAR (slot = cu+lane);
    // global source carries the inverse swizzle: h = (s&3) ^ ((r>>1)&3).
    auto stageA = [&](int nb, int kh, int kcol) {
#pragma unroll
        for (int q = 0; q < 2; ++q) {
            int cu = q * 512 + wave * 64;
            int s  = cu + lane;
            int r  = s >> 2;
            int h  = (s & 3) ^ ((r >> 1) & 3);
            gload16(A + (size_t)(m0 + r) * IN_F + kcol + h * 8,
                    &lds[(size_t)nb * 32768 + kh * 8192 + cu * 8]);
        }
    };
    auto stageB = [&](int nb, int kh, int kcol) {
#pragma unroll
        for (int q = 0; q < 2; ++q) {
            int cu = q * 512 + wave * 64;
            int s  = cu + lane;
            int r  = s >> 2;
            int h  = (s & 3) ^ ((r >> 1) & 3);
            gload16(B + (size_t)(n0 + r) * IN_F + kcol + h * 8,
                    &lds[(size_t)nb * 32768 + 16384 + kh * 8192 + cu * 8]);
        }
    };

    // prologue: tile0 fully + A(1,k0); drain tile0-k0 (vmcnt 10->6)
    stageA(0, 0, 0);
    stageB(0, 0, 0);
    stageA(0, 1, 32);
    stageB(0, 1, 32);
    stageA(1, 0, BK);
    VMCNT6;
    BAR;

    // Steady-state ledger (each stage = 2 loads, vmcnt counts per-wave loads):
    //   issue:  T-1.ph3: A(T+1,k0) | T.ph0: B(T+1,k0) | T.ph1: A(T+1,k1)
    //         | T.ph2: B(T+1,k1)   | T.ph3: A(T+2,k0)
    //   VMCNT6 @ph1: 10 in flight -> drains A(T,k1),B(T,k1)   (read at ph2/ph3)
    //   VMCNT6 @ph3: 10 in flight -> drains A(T+1,k0),B(T+1,k0) (read at T+1.ph0)
    //   leads: 4-5 phases > HBM latency. WAR: ph3's A(T+2,k0) targets buf b's
    //   A-k0 region, last read at ph0/ph1 of this tile (done, barriers passed).
    for (int T = 0; T < NT; ++T) {
        const int b   = T & 1;
        const int nb  = b ^ 1;
        const int kn1 = ((T + 1) & (NT - 1)) * BK;   // wraps at tail (discarded)
        const int kn2 = ((T + 2) & (NT - 1)) * BK;
        bf16x8 afr[4], bfr[4];

        // ph0
        DS_B(0) DS_A(0, 0)
        stageB(nb, 0, kn1);
        BAR; MFMA16(0) BAR;

        // ph1
        DS_A(0, 1)
        stageA(nb, 1, kn1 + 32);
        VMCNT6;
        BAR; MFMA16(1) BAR;

        // ph2
        DS_B(1) DS_A(1, 0)
        stageB(nb, 1, kn1 + 32);
        BAR; MFMA16(0) BAR;

        // ph3
        DS_A(1, 1)
        stageA(b, 0, kn2);
        VMCNT6;
        BAR; MFMA16(1) BAR;
    }
    VMCNT0;   // don't exit with LDS-DMA in flight

    // epilogue: C = acc + bias. C/D map: col=lane&15, row=(lane>>4)*4+v
#pragma unroll
    for (int nf = 0; nf < 4; ++nf) {
        int col = n0 + wc * 64 + nf * 16 + rl;
        float bv = bias[col];
#pragma unroll
        for (int mfa = 0; mfa < 8; ++mfa) {
            int rbase = m0 + wr * 128 + mfa * 16 + (hh << 2);
#pragma unroll
            for (int v = 0; v < 4; ++v)
                C[(size_t)(rbase + v) * OUT_F + col] = acc[mfa][nf][v] + bv;
        }
    }
}

extern "C" void kernel_launch(void* const* d_in, const int* in_sizes, int n_in,
                              void* d_out, int out_size, void* d_ws, size_t ws_size,
                              hipStream_t stream) {
    const float* x     = (const float*)d_in[0];
    const int*   Wq    = (const int*)d_in[1];
    const float* scale = (const float*)d_in[2];
    const float* zero  = (const float*)d_in[3];
    const float* bias  = (const float*)d_in[4];
    float* out = (float*)d_out;

    ushort* xb   = (ushort*)d_ws;                            // 32 MB
    ushort* West = (ushort*)d_ws + (size_t)MROWS * IN_F;     // 32 MB

    prep<<<CONV_BLK + DQ_BLK, 256, 0, stream>>>(x, xb, Wq, scale, zero, West);
    gemm_bt<<<(MROWS / BM) * (OUT_F / BN), 512, 0, stream>>>(xb, West, bias, out);
}